// Round 1
// baseline (181.994 us; speedup 1.0000x reference)
//
#include <hip/hip_runtime.h>
#include <math.h>

typedef __bf16 bf16;
typedef __attribute__((ext_vector_type(8))) __bf16 bf16x8;
typedef __attribute__((ext_vector_type(4))) __bf16 bf16x4;
typedef __attribute__((ext_vector_type(4))) float f32x4;

#define MFMA(a, b, c) __builtin_amdgcn_mfma_f32_16x16x32_bf16((a), (b), (c), 0, 0, 0)

static constexpr int NB = 16384;   // batch
static constexpr int NC = 512;     // feature dim
static constexpr int NH = 128;     // bottleneck
static constexpr int ND = 3;       // domains
static constexpr int NT = 1380;    // text rows
static constexpr int NTP = 1408;   // padded to 128

// ---------------------------------------------------------------------------
// prep: text row-normalize -> bf16 (padded, zeroed); W1/W2 transpose -> n-major
// bf16; X f32 -> bf16.
// grid = 1408 + 384 + 1536 + 2048 = 5376 blocks x 64 threads
// ---------------------------------------------------------------------------
__global__ __launch_bounds__(64) void k_prep(
    const float* __restrict__ X, const float* __restrict__ W1,
    const float* __restrict__ W2, const float* __restrict__ txt,
    bf16* __restrict__ Xbf, bf16* __restrict__ W1t,
    bf16* __restrict__ W2t, bf16* __restrict__ Tbf)
{
  const int b = blockIdx.x, t = threadIdx.x;
  if (b < NTP) {
    bf16x4* dst = (bf16x4*)(Tbf + (size_t)b * NC);
    if (b < NT) {
      const float4* src = (const float4*)(txt + (size_t)b * NC);
      float4 u0 = src[t * 2], u1 = src[t * 2 + 1];
      float ssq = u0.x * u0.x + u0.y * u0.y + u0.z * u0.z + u0.w * u0.w +
                  u1.x * u1.x + u1.y * u1.y + u1.z * u1.z + u1.w * u1.w;
      for (int m = 32; m; m >>= 1) ssq += __shfl_xor(ssq, m, 64);
      float inv = 1.0f / sqrtf(ssq);
      bf16x4 o0 = {(bf16)(u0.x * inv), (bf16)(u0.y * inv), (bf16)(u0.z * inv), (bf16)(u0.w * inv)};
      bf16x4 o1 = {(bf16)(u1.x * inv), (bf16)(u1.y * inv), (bf16)(u1.z * inv), (bf16)(u1.w * inv)};
      dst[t * 2] = o0; dst[t * 2 + 1] = o1;
    } else {
      bf16x4 z = {(bf16)0.f, (bf16)0.f, (bf16)0.f, (bf16)0.f};
      dst[t * 2] = z; dst[t * 2 + 1] = z;
    }
  } else if (b < NTP + ND * NH) {
    const int id = b - NTP, d = id >> 7, n = id & (NH - 1);
    const float* src = W1 + (size_t)d * NC * NH + n;   // stride NH over i
    bf16* dst = W1t + ((size_t)d * NH + n) * NC;       // W1t[d][n][i]
    for (int i = t; i < NC; i += 64) dst[i] = (bf16)src[(size_t)i * NH];
  } else if (b < NTP + ND * NH + ND * NC) {
    const int id = b - (NTP + ND * NH), d = id >> 9, n = id & (NC - 1);
    const float* src = W2 + (size_t)d * NH * NC + n;   // stride NC over j
    bf16* dst = W2t + ((size_t)d * NC + n) * NH;       // W2t[d][n][j]
    for (int i = t; i < NH; i += 64) dst[i] = (bf16)src[(size_t)i * NC];
  } else {
    const int id = b - (NTP + ND * NH + ND * NC);      // 0..2047
    const float4* src = (const float4*)X;
    bf16x4* dst = (bf16x4*)Xbf;
    const size_t base = (size_t)id * 1024 + (size_t)t * 16;
    for (int i = 0; i < 16; ++i) {
      float4 u = src[base + i];
      bf16x4 o = {(bf16)u.x, (bf16)u.y, (bf16)u.z, (bf16)u.w};
      dst[base + i] = o;
    }
  }
}

// ---------------------------------------------------------------------------
// gemm1: H[d] = relu(X @ W1[d])  (dense over all 3 domains)
// grid (128, 3) x 256 threads. Block tile 128 rows x 128 cols, wave = 64x64.
// ---------------------------------------------------------------------------
__global__ __launch_bounds__(256) void k_gemm1(
    const bf16* __restrict__ Xbf, const bf16* __restrict__ W1t,
    bf16* __restrict__ Hbf)
{
  const int bx = blockIdx.x, d = blockIdx.y;
  const int t = threadIdx.x, w = t >> 6, l = t & 63;
  const int wr = w >> 1, wc = w & 1;
  const int lr = l & 15, lg = l >> 4;
  const int row0 = bx * 128 + wr * 64;
  const int col0 = wc * 64;
  const bf16* A = Xbf + (size_t)row0 * NC;
  const bf16* Bm = W1t + (size_t)d * NH * NC + (size_t)col0 * NC;
  f32x4 acc[4][4] = {};
  for (int ks = 0; ks < 16; ++ks) {
    const int k0 = ks * 32 + lg * 8;
    bf16x8 a[4], bq[4];
    for (int m = 0; m < 4; ++m) a[m]  = *(const bf16x8*)(A  + (size_t)(m * 16 + lr) * NC + k0);
    for (int n = 0; n < 4; ++n) bq[n] = *(const bf16x8*)(Bm + (size_t)(n * 16 + lr) * NC + k0);
    for (int m = 0; m < 4; ++m)
      for (int n = 0; n < 4; ++n)
        acc[m][n] = MFMA(a[m], bq[n], acc[m][n]);
  }
  bf16* Hd = Hbf + (size_t)d * NB * NH;
  for (int m = 0; m < 4; ++m)
    for (int n = 0; n < 4; ++n)
      for (int r = 0; r < 4; ++r) {
        const int row = row0 + m * 16 + lg * 4 + r;
        const int col = col0 + n * 16 + lr;
        float v = acc[m][n][r];
        Hd[(size_t)row * NH + col] = (bf16)(v > 0.f ? v : 0.f);
      }
}

// ---------------------------------------------------------------------------
// gemm2: a = relu(H[d] @ W2[d]) for d = label[row] (computed dense, routed
// select), fused blend 0.2*a + 0.8*x, fused row-normalize -> feats bf16.
// grid 256 x 512 threads. Block = 64 rows x 512 cols (full row for norm),
// wave w owns cols [w*64, w*64+64).
// ---------------------------------------------------------------------------
__global__ __launch_bounds__(512) void k_gemm2(
    const bf16* __restrict__ Hbf, const bf16* __restrict__ W2t,
    const float* __restrict__ X, const int* __restrict__ lab,
    bf16* __restrict__ Fbf)
{
  __shared__ float rssq[8][64];
  __shared__ int slab[64];
  const int bx = blockIdx.x;
  const int t = threadIdx.x, w = t >> 6, l = t & 63;
  const int lr = l & 15, lg = l >> 4;
  const int row0 = bx * 64;
  const int col0 = w * 64;
  if (t < 64) slab[t] = lab[row0 + t];
  __syncthreads();

  f32x4 sel[4][4] = {};   // routed adapter output, later blended values
  for (int d = 0; d < ND; ++d) {
    f32x4 acc[4][4] = {};
    const bf16* A = Hbf + ((size_t)d * NB + row0) * NH;
    const bf16* Bm = W2t + ((size_t)d * NC + col0) * NH;
    for (int ks = 0; ks < 4; ++ks) {
      const int k0 = ks * 32 + lg * 8;
      bf16x8 a[4], bq[4];
      for (int m = 0; m < 4; ++m) a[m]  = *(const bf16x8*)(A  + (size_t)(m * 16 + lr) * NH + k0);
      for (int n = 0; n < 4; ++n) bq[n] = *(const bf16x8*)(Bm + (size_t)(n * 16 + lr) * NH + k0);
      for (int m = 0; m < 4; ++m)
        for (int n = 0; n < 4; ++n)
          acc[m][n] = MFMA(a[m], bq[n], acc[m][n]);
    }
    for (int m = 0; m < 4; ++m)
      for (int r = 0; r < 4; ++r) {
        const int rl = m * 16 + lg * 4 + r;
        const bool s = (slab[rl] == d);
        for (int n = 0; n < 4; ++n) {
          float v = acc[m][n][r];
          v = v > 0.f ? v : 0.f;
          if (s) sel[m][n][r] = v;
        }
      }
  }

  // blend with image features; per-row sum-of-squares (deterministic:
  // per-wave partials, fixed-order sum)
  for (int m = 0; m < 4; ++m)
    for (int r = 0; r < 4; ++r) {
      const int rl = m * 16 + lg * 4 + r;
      const size_t row = row0 + rl;
      float part = 0.f;
      for (int n = 0; n < 4; ++n) {
        const int col = col0 + n * 16 + lr;
        float v = 0.2f * sel[m][n][r] + 0.8f * X[row * NC + col];
        sel[m][n][r] = v;
        part += v * v;
      }
      part += __shfl_xor(part, 1, 64);
      part += __shfl_xor(part, 2, 64);
      part += __shfl_xor(part, 4, 64);
      part += __shfl_xor(part, 8, 64);
      if (lr == 0) rssq[w][rl] = part;
    }
  __syncthreads();
  for (int m = 0; m < 4; ++m)
    for (int r = 0; r < 4; ++r) {
      const int rl = m * 16 + lg * 4 + r;
      float tot = 0.f;
      for (int ww = 0; ww < 8; ++ww) tot += rssq[ww][rl];
      const float inv = 1.0f / sqrtf(tot);
      const size_t row = row0 + rl;
      for (int n = 0; n < 4; ++n) {
        const int col = col0 + n * 16 + lr;
        Fbf[row * NC + col] = (bf16)(sel[m][n][r] * inv);
      }
    }
}

// ---------------------------------------------------------------------------
// gemm3: out = exp(logit_scale) * feats @ txt^T   [16384 x 1380] f32
// grid (128, 11) x 256 threads. Block tile 128x128, wave 64x64.
// ---------------------------------------------------------------------------
__global__ __launch_bounds__(256) void k_gemm3(
    const bf16* __restrict__ Fbf, const bf16* __restrict__ Tbf,
    const float* __restrict__ lsc, float* __restrict__ out)
{
  const int bx = blockIdx.x, by = blockIdx.y;
  const int t = threadIdx.x, w = t >> 6, l = t & 63;
  const int wr = w >> 1, wc = w & 1;
  const int lr = l & 15, lg = l >> 4;
  const int row0 = bx * 128 + wr * 64;
  const int col0 = by * 128 + wc * 64;
  const bf16* A = Fbf + (size_t)row0 * NC;
  const bf16* Bm = Tbf + (size_t)col0 * NC;
  f32x4 acc[4][4] = {};
  for (int ks = 0; ks < 16; ++ks) {
    const int k0 = ks * 32 + lg * 8;
    bf16x8 a[4], bq[4];
    for (int m = 0; m < 4; ++m) a[m]  = *(const bf16x8*)(A  + (size_t)(m * 16 + lr) * NC + k0);
    for (int n = 0; n < 4; ++n) bq[n] = *(const bf16x8*)(Bm + (size_t)(n * 16 + lr) * NC + k0);
    for (int m = 0; m < 4; ++m)
      for (int n = 0; n < 4; ++n)
        acc[m][n] = MFMA(a[m], bq[n], acc[m][n]);
  }
  const float s = expf(lsc[0]);
  for (int m = 0; m < 4; ++m)
    for (int n = 0; n < 4; ++n)
      for (int r = 0; r < 4; ++r) {
        const int row = row0 + m * 16 + lg * 4 + r;
        const int col = col0 + n * 16 + lr;
        if (col < NT) out[(size_t)row * NT + col] = s * acc[m][n][r];
      }
}

// ---------------------------------------------------------------------------
extern "C" void kernel_launch(void* const* d_in, const int* in_sizes, int n_in,
                              void* d_out, int out_size, void* d_ws, size_t ws_size,
                              hipStream_t stream) {
  const float* X   = (const float*)d_in[0];
  const int*   lab = (const int*)d_in[1];
  const float* W1  = (const float*)d_in[2];
  const float* W2  = (const float*)d_in[3];
  const float* txt = (const float*)d_in[4];
  const float* lsc = (const float*)d_in[5];
  float* out = (float*)d_out;

  char* ws = (char*)d_ws;
  constexpr size_t SZ_XBF = (size_t)NB * NC * 2;        // 16,777,216
  constexpr size_t SZ_W1T = (size_t)ND * NH * NC * 2;   //    393,216
  constexpr size_t SZ_W2T = (size_t)ND * NC * NH * 2;   //    393,216
  constexpr size_t SZ_HBF = (size_t)ND * NB * NH * 2;   // 12,582,912
  constexpr size_t SZ_TBF = (size_t)NTP * NC * 2;       //  1,441,792
  bf16* Xbf = (bf16*)(ws);
  bf16* W1t = (bf16*)(ws + SZ_XBF);
  bf16* W2t = (bf16*)(ws + SZ_XBF + SZ_W1T);
  bf16* Hbf = (bf16*)(ws + SZ_XBF + SZ_W1T + SZ_W2T);
  bf16* Tbf = (bf16*)(ws + SZ_XBF + SZ_W1T + SZ_W2T + SZ_HBF);
  bf16* Fbf = (bf16*)(ws + SZ_XBF + SZ_W1T + SZ_W2T + SZ_HBF + SZ_TBF);

  k_prep<<<NTP + ND * NH + ND * NC + 2048, 64, 0, stream>>>(X, W1, W2, txt,
                                                            Xbf, W1t, W2t, Tbf);
  k_gemm1<<<dim3(NB / 128, ND), 256, 0, stream>>>(Xbf, W1t, Hbf);
  k_gemm2<<<NB / 64, 512, 0, stream>>>(Hbf, W2t, X, lab, Fbf);
  k_gemm3<<<dim3(NB / 128, NTP / 128), 256, 0, stream>>>(Fbf, Tbf, lsc, out);
}

// Round 2
// 109.963 us; speedup vs baseline: 1.6550x; 1.6550x over previous
//
#include <hip/hip_runtime.h>
#include <math.h>

typedef __bf16 bf16;
typedef __attribute__((ext_vector_type(8))) __bf16 bf16x8;
typedef __attribute__((ext_vector_type(4))) __bf16 bf16x4;
typedef __attribute__((ext_vector_type(4))) float f32x4;

#define MFMA(a, b, c) __builtin_amdgcn_mfma_f32_16x16x32_bf16((a), (b), (c), 0, 0, 0)

static constexpr int NB = 16384;   // batch
static constexpr int NC = 512;     // feature dim
static constexpr int NH = 128;     // bottleneck
static constexpr int ND = 3;       // domains
static constexpr int NT = 1380;    // text rows
static constexpr int NTP = 1408;   // padded to 128

// ---------------------------------------------------------------------------
// prep: text row-normalize -> bf16 (padded, zeroed); W1/W2 transpose -> n-major
// bf16; X f32 -> bf16.
// ---------------------------------------------------------------------------
__global__ __launch_bounds__(64) void k_prep(
    const float* __restrict__ X, const float* __restrict__ W1,
    const float* __restrict__ W2, const float* __restrict__ txt,
    bf16* __restrict__ Xbf, bf16* __restrict__ W1t,
    bf16* __restrict__ W2t, bf16* __restrict__ Tbf)
{
  const int b = blockIdx.x, t = threadIdx.x;
  if (b < NTP) {
    bf16x4* dst = (bf16x4*)(Tbf + (size_t)b * NC);
    if (b < NT) {
      const float4* src = (const float4*)(txt + (size_t)b * NC);
      float4 u0 = src[t * 2], u1 = src[t * 2 + 1];
      float ssq = u0.x * u0.x + u0.y * u0.y + u0.z * u0.z + u0.w * u0.w +
                  u1.x * u1.x + u1.y * u1.y + u1.z * u1.z + u1.w * u1.w;
      for (int m = 32; m; m >>= 1) ssq += __shfl_xor(ssq, m, 64);
      float inv = 1.0f / sqrtf(ssq);
      bf16x4 o0 = {(bf16)(u0.x * inv), (bf16)(u0.y * inv), (bf16)(u0.z * inv), (bf16)(u0.w * inv)};
      bf16x4 o1 = {(bf16)(u1.x * inv), (bf16)(u1.y * inv), (bf16)(u1.z * inv), (bf16)(u1.w * inv)};
      dst[t * 2] = o0; dst[t * 2 + 1] = o1;
    } else {
      bf16x4 z = {(bf16)0.f, (bf16)0.f, (bf16)0.f, (bf16)0.f};
      dst[t * 2] = z; dst[t * 2 + 1] = z;
    }
  } else if (b < NTP + ND * NH) {
    const int id = b - NTP, d = id >> 7, n = id & (NH - 1);
    const float* src = W1 + (size_t)d * NC * NH + n;   // stride NH over i
    bf16* dst = W1t + ((size_t)d * NH + n) * NC;       // W1t[d][n][i]
    for (int i = t; i < NC; i += 64) dst[i] = (bf16)src[(size_t)i * NH];
  } else if (b < NTP + ND * NH + ND * NC) {
    const int id = b - (NTP + ND * NH), d = id >> 9, n = id & (NC - 1);
    const float* src = W2 + (size_t)d * NH * NC + n;   // stride NC over j
    bf16* dst = W2t + ((size_t)d * NC + n) * NH;       // W2t[d][n][j]
    for (int i = t; i < NH; i += 64) dst[i] = (bf16)src[(size_t)i * NC];
  } else {
    const int id = b - (NTP + ND * NH + ND * NC);      // 0..2047
    const float4* src = (const float4*)X;
    bf16x4* dst = (bf16x4*)Xbf;
    const size_t base = (size_t)id * 1024 + (size_t)t * 16;
    for (int i = 0; i < 16; ++i) {
      float4 u = src[base + i];
      bf16x4 o = {(bf16)u.x, (bf16)u.y, (bf16)u.z, (bf16)u.w};
      dst[base + i] = o;
    }
  }
}

// ---------------------------------------------------------------------------
// m97-structure staging: one 128x32 bf16 tile (8 KiB) from row-major global
// (leading dim 512) into linear LDS via global_load_lds width 16.
// 256 threads x 2 issues x 16 B = 8 KiB. LDS dest is linear in thread id
// (wave-uniform base + lane*16), matching the HW constraint.
// ---------------------------------------------------------------------------
__device__ __forceinline__ void stage32(const bf16* __restrict__ g, bf16* lds, int t) {
#pragma unroll
  for (int i = 0; i < 2; ++i) {
    const int off = (i * 256 + t) * 16;    // byte offset in 8 KiB tile
    const int row = off >> 6;              // 64 B per row (32 bf16)
    const int colb = off & 63;
    __builtin_amdgcn_global_load_lds(
        (const __attribute__((address_space(1))) void*)(g + (size_t)row * NC + (colb >> 1)),
        (__attribute__((address_space(3))) void*)((char*)lds + off),
        16, 0, 0);
  }
}

// ---------------------------------------------------------------------------
// gemm1: H[d] = relu(X @ W1[d])  (dense over all 3 domains)
// grid (128, 3) x 256. 128x128 tile, BK=32, double-buffered LDS staging.
// ---------------------------------------------------------------------------
__global__ __launch_bounds__(256) void k_gemm1(
    const bf16* __restrict__ Xbf, const bf16* __restrict__ W1t,
    bf16* __restrict__ Hbf)
{
  __shared__ bf16 As[2][128 * 32];
  __shared__ bf16 Bs[2][128 * 32];
  const int bx = blockIdx.x, d = blockIdx.y;
  const int t = threadIdx.x, w = t >> 6, l = t & 63;
  const int wr = w >> 1, wc = w & 1;
  const int lr = l & 15, lg = l >> 4;
  const int row0 = bx * 128;
  const bf16* Ag = Xbf + (size_t)row0 * NC;
  const bf16* Bg = W1t + (size_t)d * NH * NC;   // 128 rows, ld = NC
  f32x4 acc[4][4] = {};
  stage32(Ag, As[0], t);
  stage32(Bg, Bs[0], t);
  for (int ks = 0; ks < 16; ++ks) {
    const int cur = ks & 1;
    __syncthreads();                       // drains stage(cur)
    if (ks + 1 < 16) {
      stage32(Ag + (ks + 1) * 32, As[cur ^ 1], t);
      stage32(Bg + (ks + 1) * 32, Bs[cur ^ 1], t);
    }
    bf16x8 a[4], bq[4];
#pragma unroll
    for (int m = 0; m < 4; ++m) a[m]  = *(const bf16x8*)&As[cur][(wr * 64 + m * 16 + lr) * 32 + lg * 8];
#pragma unroll
    for (int n = 0; n < 4; ++n) bq[n] = *(const bf16x8*)&Bs[cur][(wc * 64 + n * 16 + lr) * 32 + lg * 8];
#pragma unroll
    for (int m = 0; m < 4; ++m)
#pragma unroll
      for (int n = 0; n < 4; ++n)
        acc[m][n] = MFMA(a[m], bq[n], acc[m][n]);
  }
  bf16* Hd = Hbf + (size_t)d * NB * NH;
#pragma unroll
  for (int m = 0; m < 4; ++m)
#pragma unroll
    for (int n = 0; n < 4; ++n)
#pragma unroll
      for (int r = 0; r < 4; ++r) {
        const int row = row0 + wr * 64 + m * 16 + lg * 4 + r;
        const int col = wc * 64 + n * 16 + lr;
        float v = acc[m][n][r];
        Hd[(size_t)row * NH + col] = (bf16)(v > 0.f ? v : 0.f);
      }
}

// ---------------------------------------------------------------------------
// gemm2: a = relu(H[d] @ W2[d]) for d = label[row] (dense compute, routed
// select), fused blend + row-normalize -> feats bf16. (unchanged this round)
// ---------------------------------------------------------------------------
__global__ __launch_bounds__(512) void k_gemm2(
    const bf16* __restrict__ Hbf, const bf16* __restrict__ W2t,
    const float* __restrict__ X, const int* __restrict__ lab,
    bf16* __restrict__ Fbf)
{
  __shared__ float rssq[8][64];
  __shared__ int slab[64];
  const int bx = blockIdx.x;
  const int t = threadIdx.x, w = t >> 6, l = t & 63;
  const int lr = l & 15, lg = l >> 4;
  const int row0 = bx * 64;
  const int col0 = w * 64;
  if (t < 64) slab[t] = lab[row0 + t];
  __syncthreads();

  f32x4 sel[4][4] = {};
  for (int d = 0; d < ND; ++d) {
    f32x4 acc[4][4] = {};
    const bf16* A = Hbf + ((size_t)d * NB + row0) * NH;
    const bf16* Bm = W2t + ((size_t)d * NC + col0) * NH;
    for (int ks = 0; ks < 4; ++ks) {
      const int k0 = ks * 32 + lg * 8;
      bf16x8 a[4], bq[4];
      for (int m = 0; m < 4; ++m) a[m]  = *(const bf16x8*)(A  + (size_t)(m * 16 + lr) * NH + k0);
      for (int n = 0; n < 4; ++n) bq[n] = *(const bf16x8*)(Bm + (size_t)(n * 16 + lr) * NH + k0);
      for (int m = 0; m < 4; ++m)
        for (int n = 0; n < 4; ++n)
          acc[m][n] = MFMA(a[m], bq[n], acc[m][n]);
    }
    for (int m = 0; m < 4; ++m)
      for (int r = 0; r < 4; ++r) {
        const int rl = m * 16 + lg * 4 + r;
        const bool s = (slab[rl] == d);
        for (int n = 0; n < 4; ++n) {
          float v = acc[m][n][r];
          v = v > 0.f ? v : 0.f;
          if (s) sel[m][n][r] = v;
        }
      }
  }

  for (int m = 0; m < 4; ++m)
    for (int r = 0; r < 4; ++r) {
      const int rl = m * 16 + lg * 4 + r;
      const size_t row = row0 + rl;
      float part = 0.f;
      for (int n = 0; n < 4; ++n) {
        const int col = col0 + n * 16 + lr;
        float v = 0.2f * sel[m][n][r] + 0.8f * X[row * NC + col];
        sel[m][n][r] = v;
        part += v * v;
      }
      part += __shfl_xor(part, 1, 64);
      part += __shfl_xor(part, 2, 64);
      part += __shfl_xor(part, 4, 64);
      part += __shfl_xor(part, 8, 64);
      if (lr == 0) rssq[w][rl] = part;
    }
  __syncthreads();
  for (int m = 0; m < 4; ++m)
    for (int r = 0; r < 4; ++r) {
      const int rl = m * 16 + lg * 4 + r;
      float tot = 0.f;
      for (int ww = 0; ww < 8; ++ww) tot += rssq[ww][rl];
      const float inv = 1.0f / sqrtf(tot);
      const size_t row = row0 + rl;
      for (int n = 0; n < 4; ++n) {
        const int col = col0 + n * 16 + lr;
        Fbf[row * NC + col] = (bf16)(sel[m][n][r] * inv);
      }
    }
}

// ---------------------------------------------------------------------------
// gemm3: out = exp(logit_scale) * feats @ txt^T   [16384 x 1380] f32
// grid (128, 11) x 256. 128x128 tile, BK=32, double-buffered LDS staging.
// ---------------------------------------------------------------------------
__global__ __launch_bounds__(256) void k_gemm3(
    const bf16* __restrict__ Fbf, const bf16* __restrict__ Tbf,
    const float* __restrict__ lsc, float* __restrict__ out)
{
  __shared__ bf16 As[2][128 * 32];
  __shared__ bf16 Bs[2][128 * 32];
  const int bx = blockIdx.x, by = blockIdx.y;
  const int t = threadIdx.x, w = t >> 6, l = t & 63;
  const int wr = w >> 1, wc = w & 1;
  const int lr = l & 15, lg = l >> 4;
  const int row0 = bx * 128;
  const int col0 = by * 128;
  const bf16* Ag = Fbf + (size_t)row0 * NC;
  const bf16* Bg = Tbf + (size_t)col0 * NC;
  f32x4 acc[4][4] = {};
  stage32(Ag, As[0], t);
  stage32(Bg, Bs[0], t);
  for (int ks = 0; ks < 16; ++ks) {
    const int cur = ks & 1;
    __syncthreads();
    if (ks + 1 < 16) {
      stage32(Ag + (ks + 1) * 32, As[cur ^ 1], t);
      stage32(Bg + (ks + 1) * 32, Bs[cur ^ 1], t);
    }
    bf16x8 a[4], bq[4];
#pragma unroll
    for (int m = 0; m < 4; ++m) a[m]  = *(const bf16x8*)&As[cur][(wr * 64 + m * 16 + lr) * 32 + lg * 8];
#pragma unroll
    for (int n = 0; n < 4; ++n) bq[n] = *(const bf16x8*)&Bs[cur][(wc * 64 + n * 16 + lr) * 32 + lg * 8];
#pragma unroll
    for (int m = 0; m < 4; ++m)
#pragma unroll
      for (int n = 0; n < 4; ++n)
        acc[m][n] = MFMA(a[m], bq[n], acc[m][n]);
  }
  const float s = expf(lsc[0]);
#pragma unroll
  for (int m = 0; m < 4; ++m)
#pragma unroll
    for (int n = 0; n < 4; ++n)
#pragma unroll
      for (int r = 0; r < 4; ++r) {
        const int row = row0 + wr * 64 + m * 16 + lg * 4 + r;
        const int col = col0 + wc * 64 + n * 16 + lr;
        if (col < NT) out[(size_t)row * NT + col] = s * acc[m][n][r];
      }
}

// ---------------------------------------------------------------------------
extern "C" void kernel_launch(void* const* d_in, const int* in_sizes, int n_in,
                              void* d_out, int out_size, void* d_ws, size_t ws_size,
                              hipStream_t stream) {
  const float* X   = (const float*)d_in[0];
  const int*   lab = (const int*)d_in[1];
  const float* W1  = (const float*)d_in[2];
  const float* W2  = (const float*)d_in[3];
  const float* txt = (const float*)d_in[4];
  const float* lsc = (const float*)d_in[5];
  float* out = (float*)d_out;

  char* ws = (char*)d_ws;
  constexpr size_t SZ_XBF = (size_t)NB * NC * 2;        // 16,777,216
  constexpr size_t SZ_W1T = (size_t)ND * NH * NC * 2;   //    393,216
  constexpr size_t SZ_W2T = (size_t)ND * NC * NH * 2;   //    393,216
  constexpr size_t SZ_HBF = (size_t)ND * NB * NH * 2;   // 12,582,912
  constexpr size_t SZ_TBF = (size_t)NTP * NC * 2;       //  1,441,792
  bf16* Xbf = (bf16*)(ws);
  bf16* W1t = (bf16*)(ws + SZ_XBF);
  bf16* W2t = (bf16*)(ws + SZ_XBF + SZ_W1T);
  bf16* Hbf = (bf16*)(ws + SZ_XBF + SZ_W1T + SZ_W2T);
  bf16* Tbf = (bf16*)(ws + SZ_XBF + SZ_W1T + SZ_W2T + SZ_HBF);
  bf16* Fbf = (bf16*)(ws + SZ_XBF + SZ_W1T + SZ_W2T + SZ_HBF + SZ_TBF);

  k_prep<<<NTP + ND * NH + ND * NC + 2048, 64, 0, stream>>>(X, W1, W2, txt,
                                                            Xbf, W1t, W2t, Tbf);
  k_gemm1<<<dim3(NB / 128, ND), 256, 0, stream>>>(Xbf, W1t, Hbf);
  k_gemm2<<<NB / 64, 512, 0, stream>>>(Hbf, W2t, X, lab, Fbf);
  k_gemm3<<<dim3(NB / 128, NTP / 128), 256, 0, stream>>>(Fbf, Tbf, lsc, out);
}